// Round 1
// baseline (197.043 us; speedup 1.0000x reference)
//
#include <hip/hip_runtime.h>

// NCN recurrence, 2 layers. B=4, N=4096, E=128, NK=4, ce=32, CACHE=32, m=128.
// One block per (b, g) group; 128 threads = (n in [0,4)) x (o in [0,32)).
// Thread (n,o) owns xi[n,o,0:32], xa[n,o,0:32] in registers.
// Sequential scan j=0..31 with one barrier/step (double-buffered LDS row bcast).
// Gather and scatter use the same per-group row set -> blocks own rows
// exclusively -> layer 2 runs in-place on d_out.

namespace {
constexpr int kB = 4;
constexpr int kN = 4096;
constexpr int kE = 128;
constexpr int kNK = 4;
constexpr int kCE = 32;          // E / NK
constexpr int kCache = 32;
constexpr int kM = kN / kCache;  // 128 groups per batch

__device__ __forceinline__ float fast_tanh(float x) {
    // tanh(x) = (e^{2x}-1)/(e^{2x}+1); e^{2x} = 2^{x * 2*log2(e)}
    float cx = fminf(fmaxf(x, -10.0f), 10.0f);  // tanh(+-10) == +-1 to fp32
    float t = __builtin_amdgcn_exp2f(cx * 2.8853900817779268f);
    return (t - 1.0f) * __builtin_amdgcn_rcpf(t + 1.0f);
}
}  // namespace

__global__ void __launch_bounds__(128) ncn_layer_kernel(
    const float* __restrict__ x_in, const float* __restrict__ xa_in,
    const float* __restrict__ Wl,   // pointer to this layer's 256 floats
    float* __restrict__ x_out, float* __restrict__ xa_out,
    int s)                          // group stride: 0 for stage 0, 1 for stage 1
{
    const int blk = blockIdx.x;         // b * kM + g
    const int b   = blk >> 7;           // kM == 128
    const int g   = blk & (kM - 1);
    const int t   = threadIdx.x;
    const int n   = t >> 5;
    const int o   = t & 31;

    // row index: ((g + o*s) % m) * CACHE + o
    const int r = (((g + o * s) & (kM - 1)) << 5) + o;
    const size_t base = ((size_t)(b * kN + r)) * kE + n * kCE;

    float xi[kCE], xa[kCE], Wi[kCE];

    {
        const float4* xi4 = reinterpret_cast<const float4*>(x_in + base);
        const float4* xa4 = reinterpret_cast<const float4*>(xa_in + base);
        const float4* wi4 = reinterpret_cast<const float4*>(Wl + n * kCE);
#pragma unroll
        for (int q = 0; q < kCE / 4; ++q) {
            float4 v = xi4[q];
            xi[4 * q + 0] = v.x; xi[4 * q + 1] = v.y;
            xi[4 * q + 2] = v.z; xi[4 * q + 3] = v.w;
            float4 a = xa4[q];
            xa[4 * q + 0] = a.x; xa[4 * q + 1] = a.y;
            xa[4 * q + 2] = a.z; xa[4 * q + 3] = a.w;
            float4 w = wi4[q];
            Wi[4 * q + 0] = w.x; Wi[4 * q + 1] = w.y;
            Wi[4 * q + 2] = w.z; Wi[4 * q + 3] = w.w;
        }
    }

    __shared__ float xj_sh[2][kNK][kCE];   // double-buffered broadcast row
    __shared__ float dj_sh[2][kNK];        // dot(xj, Wj[n])
    __shared__ float Wj_sh[kNK * kCE];

    Wj_sh[t] = Wl[kE + t];
    __syncthreads();

    for (int j = 0; j < kCache; ++j) {
        const int p = j & 1;
        if (o == j) {
            float dj = 0.0f;
#pragma unroll
            for (int e = 0; e < kCE; ++e) {
                xj_sh[p][n][e] = xi[e];
                dj = fmaf(xi[e], Wj_sh[n * kCE + e], dj);
            }
            dj_sh[p][n] = dj;
        }
        __syncthreads();

        // sim1 = dot(xi_row, Wi[n])  (register dot, 4-way ILP)
        float s0 = 0.f, s1 = 0.f, s2 = 0.f, s3 = 0.f;
#pragma unroll
        for (int e = 0; e < kCE; e += 4) {
            s0 = fmaf(xi[e + 0], Wi[e + 0], s0);
            s1 = fmaf(xi[e + 1], Wi[e + 1], s1);
            s2 = fmaf(xi[e + 2], Wi[e + 2], s2);
            s3 = fmaf(xi[e + 3], Wi[e + 3], s3);
        }
        const float sim = (s0 + s1) + (s2 + s3) + dj_sh[p][n];
        const float hs  = 0.5f * sim;

        const float4* xj4 = reinterpret_cast<const float4*>(&xj_sh[p][n][0]);
#pragma unroll
        for (int q = 0; q < kCE / 4; ++q) {
            float4 xjv = xj4[q];
            float xje[4] = {xjv.x, xjv.y, xjv.z, xjv.w};
#pragma unroll
            for (int u = 0; u < 4; ++u) {
                const int e = 4 * q + u;
                float T = fmaf(hs, xje[u], 0.5f * xi[e]);
                float F = fast_tanh(T);
                xa[e] = fmaf(0.1f, F - xa[e], xa[e]);       // 0.9*xa + 0.1*F
                xi[e] = fmaf(0.1f, xa[e] - xi[e], xi[e]);   // 0.9*xi + 0.1*ya
            }
        }
    }

    {
        float4* xo4 = reinterpret_cast<float4*>(x_out + base);
        float4* ao4 = reinterpret_cast<float4*>(xa_out + base);
#pragma unroll
        for (int q = 0; q < kCE / 4; ++q) {
            float4 v; v.x = xi[4 * q + 0]; v.y = xi[4 * q + 1];
            v.z = xi[4 * q + 2]; v.w = xi[4 * q + 3];
            xo4[q] = v;
            float4 a; a.x = xa[4 * q + 0]; a.y = xa[4 * q + 1];
            a.z = xa[4 * q + 2]; a.w = xa[4 * q + 3];
            ao4[q] = a;
        }
    }
}

extern "C" void kernel_launch(void* const* d_in, const int* in_sizes, int n_in,
                              void* d_out, int out_size, void* d_ws, size_t ws_size,
                              hipStream_t stream) {
    const float* x  = (const float*)d_in[0];   // [B, N, E] fp32
    const float* xa = (const float*)d_in[1];   // [B, N, E] fp32
    const float* W  = (const float*)d_in[2];   // [2, 256] fp32

    float* x_out  = (float*)d_out;                       // first output
    float* xa_out = x_out + (size_t)kB * kN * kE;        // second output

    const dim3 grid(kB * kM);   // 512 blocks
    const dim3 block(128);

    // Layer 0 (stage 0, s = 0): d_in -> d_out
    ncn_layer_kernel<<<grid, block, 0, stream>>>(x, xa, W, x_out, xa_out, 0);
    // Layer 1 (stage 1, s = 1): d_out -> d_out (in-place; blocks own their rows)
    ncn_layer_kernel<<<grid, block, 0, stream>>>(x_out, xa_out, W + 2 * kE,
                                                 x_out, xa_out, 1);
}

// Round 2
// 142.085 us; speedup vs baseline: 1.3868x; 1.3868x over previous
//
#include <hip/hip_runtime.h>

// NCN recurrence, 2 layers. B=4, N=4096, E=128, NK=4, ce=32, CACHE=32, m=128.
// KEY: the n (NK) dimension is fully independent -> 2048 independent
// [cache=32 x ce=32] subproblems. One single-wave block (64 threads) per
// subproblem: lane = (h in {0,1}) x (o in {0,32}); lane owns feats
// [h*16, h*16+16) of row o. Scan j=0..31 is wave-internal: row-j broadcast
// through a 32-float LDS buffer (single-wave barrier = just a waitcnt drain),
// dot reduction via one shfl_xor(32). dj term folded into the same reduction
// (every lane recomputes its 16-wide Wj partial; exec-masked alternative
// costs identical wave time).
// Blocks own disjoint (row, feat-slice) sets -> layer 1 runs in-place.

namespace {
constexpr int kB = 4;
constexpr int kN = 4096;
constexpr int kE = 128;
constexpr int kCE = 32;          // E / NK
constexpr int kH  = 16;          // feats per lane (ce / 2)
constexpr int kCache = 32;
constexpr int kM = kN / kCache;  // 128 groups per batch
}  // namespace

__global__ void __launch_bounds__(64) ncn_layer_kernel(
    const float* __restrict__ x_in, const float* __restrict__ xa_in,
    const float* __restrict__ Wl,   // this layer's 256 floats
    float* __restrict__ x_out, float* __restrict__ xa_out,
    int s)                          // group stride: 0 for stage 0, 1 for stage 1
{
    const int blk = blockIdx.x;         // ((b*128 + g)*4 + n)
    const int n   = blk & 3;
    const int g   = (blk >> 2) & (kM - 1);
    const int b   = blk >> 9;
    const int t   = threadIdx.x;        // 0..63
    const int o   = t & 31;
    const int h   = t >> 5;

    // row index: ((g + o*s) % m) * CACHE + o
    const int r = (((g + o * s) & (kM - 1)) << 5) + o;
    const size_t base = ((size_t)(b * kN + r)) * kE + n * kCE + h * kH;

    float xi[kH], xa[kH], wi[kH], wj[kH];

    {
        const float4* xi4 = reinterpret_cast<const float4*>(x_in + base);
        const float4* xa4 = reinterpret_cast<const float4*>(xa_in + base);
        const float4* wi4 = reinterpret_cast<const float4*>(Wl + n * kCE + h * kH);
        const float4* wj4 = reinterpret_cast<const float4*>(Wl + kE + n * kCE + h * kH);
#pragma unroll
        for (int q = 0; q < kH / 4; ++q) {
            float4 v = xi4[q];
            xi[4 * q + 0] = v.x; xi[4 * q + 1] = v.y;
            xi[4 * q + 2] = v.z; xi[4 * q + 3] = v.w;
            float4 a = xa4[q];
            xa[4 * q + 0] = a.x; xa[4 * q + 1] = a.y;
            xa[4 * q + 2] = a.z; xa[4 * q + 3] = a.w;
            float4 u = wi4[q];
            wi[4 * q + 0] = u.x; wi[4 * q + 1] = u.y;
            wi[4 * q + 2] = u.z; wi[4 * q + 3] = u.w;
            float4 w = wj4[q];
            wj[4 * q + 0] = w.x; wj[4 * q + 1] = w.y;
            wj[4 * q + 2] = w.z; wj[4 * q + 3] = w.w;
        }
    }

    __shared__ float xj_sh[kCE];        // [h*16 + e] broadcast row slice

    for (int j = 0; j < kCache; ++j) {
        if (o == j) {
            float4* w4 = reinterpret_cast<float4*>(&xj_sh[h * kH]);
#pragma unroll
            for (int q = 0; q < kH / 4; ++q) {
                float4 v;
                v.x = xi[4 * q + 0]; v.y = xi[4 * q + 1];
                v.z = xi[4 * q + 2]; v.w = xi[4 * q + 3];
                w4[q] = v;
            }
        }
        __syncthreads();   // single-wave: waitcnt drain only

        float xj[kH];
        {
            const float4* r4 = reinterpret_cast<const float4*>(&xj_sh[h * kH]);
#pragma unroll
            for (int q = 0; q < kH / 4; ++q) {
                float4 v = r4[q];
                xj[4 * q + 0] = v.x; xj[4 * q + 1] = v.y;
                xj[4 * q + 2] = v.z; xj[4 * q + 3] = v.w;
            }
        }

        // partial = dot16(xi_row, Wi_half) + dot16(xj, Wj_half); 4-way ILP
        float s0 = 0.f, s1 = 0.f, s2 = 0.f, s3 = 0.f;
#pragma unroll
        for (int e = 0; e < kH; e += 4) {
            s0 = fmaf(xi[e + 0], wi[e + 0], s0);
            s1 = fmaf(xi[e + 1], wi[e + 1], s1);
            s2 = fmaf(xi[e + 2], wi[e + 2], s2);
            s3 = fmaf(xi[e + 3], wi[e + 3], s3);
        }
#pragma unroll
        for (int e = 0; e < kH; e += 4) {
            s0 = fmaf(xj[e + 0], wj[e + 0], s0);
            s1 = fmaf(xj[e + 1], wj[e + 1], s1);
            s2 = fmaf(xj[e + 2], wj[e + 2], s2);
            s3 = fmaf(xj[e + 3], wj[e + 3], s3);
        }
        float part = (s0 + s1) + (s2 + s3);
        float sim  = part + __shfl_xor(part, 32, 64);
        const float hs = 0.5f * sim;

#pragma unroll
        for (int e = 0; e < kH; ++e) {
            float T = fmaf(hs, xj[e], 0.5f * xi[e]);
            // tanh(T) = 1 - 2/(e^{2T}+1)
            float cx = fminf(fmaxf(T, -10.0f), 10.0f);
            float t2 = __builtin_amdgcn_exp2f(cx * 2.8853900817779268f);
            float F  = fmaf(-2.0f, __builtin_amdgcn_rcpf(t2 + 1.0f), 1.0f);
            xa[e] = fmaf(0.1f, F - xa[e], xa[e]);       // 0.9*xa + 0.1*F
            xi[e] = fmaf(0.1f, xa[e] - xi[e], xi[e]);   // 0.9*xi + 0.1*ya
        }
    }

    {
        float4* xo4 = reinterpret_cast<float4*>(x_out + base);
        float4* ao4 = reinterpret_cast<float4*>(xa_out + base);
#pragma unroll
        for (int q = 0; q < kH / 4; ++q) {
            float4 v;
            v.x = xi[4 * q + 0]; v.y = xi[4 * q + 1];
            v.z = xi[4 * q + 2]; v.w = xi[4 * q + 3];
            xo4[q] = v;
            float4 a;
            a.x = xa[4 * q + 0]; a.y = xa[4 * q + 1];
            a.z = xa[4 * q + 2]; a.w = xa[4 * q + 3];
            ao4[q] = a;
        }
    }
}

extern "C" void kernel_launch(void* const* d_in, const int* in_sizes, int n_in,
                              void* d_out, int out_size, void* d_ws, size_t ws_size,
                              hipStream_t stream) {
    const float* x  = (const float*)d_in[0];   // [B, N, E] fp32
    const float* xa = (const float*)d_in[1];   // [B, N, E] fp32
    const float* W  = (const float*)d_in[2];   // [2, 256] fp32

    float* x_out  = (float*)d_out;                       // first output
    float* xa_out = x_out + (size_t)kB * kN * kE;        // second output

    const dim3 grid(kB * kM * 4);   // 2048 single-wave blocks
    const dim3 block(64);

    // Layer 0 (stage 0, s = 0): d_in -> d_out
    ncn_layer_kernel<<<grid, block, 0, stream>>>(x, xa, W, x_out, xa_out, 0);
    // Layer 1 (stage 1, s = 1): d_out -> d_out (in-place; blocks own disjoint slices)
    ncn_layer_kernel<<<grid, block, 0, stream>>>(x_out, xa_out, W + 2 * kE,
                                                 x_out, xa_out, 1);
}

// Round 3
// 134.928 us; speedup vs baseline: 1.4604x; 1.0530x over previous
//
#include <hip/hip_runtime.h>

// NCN recurrence, 2 layers. B=4, N=4096, E=128, NK=4, ce=32, CACHE=32, m=128.
// 2048 independent [32 x 32] subproblems (n-dim is independent). One
// single-wave block per subproblem; lane (h,o) owns feats [h*16,h*16+16) of
// row o. Scan j=0..31:
//   - row-j broadcast via 16x ds_bpermute from lane (h*32+j): NO LDS buffer,
//     NO barrier -> compiler can software-pipeline across scan steps.
//     (bpermute's vsrc operand is each lane's own xi[e] register, so the
//     use-def chain orders it after the previous step's update.)
//   - sim reduction: one shfl_xor(32) combining Wi and Wj half-dots.
//   - tanh(T) = 1 - 2/(exp2(2*log2e*T)+1), UNclamped: exp2 overflow->inf
//     and underflow->0 both give the exact +-1 limit.
// Blocks own disjoint (row, feat-slice) sets -> layer 1 runs in-place.

namespace {
constexpr int kB = 4;
constexpr int kN = 4096;
constexpr int kE = 128;
constexpr int kCE = 32;          // E / NK
constexpr int kH  = 16;          // feats per lane (ce / 2)
constexpr int kCache = 32;
constexpr int kM = kN / kCache;  // 128 groups per batch
}  // namespace

__global__ void __launch_bounds__(64) ncn_layer_kernel(
    const float* __restrict__ x_in, const float* __restrict__ xa_in,
    const float* __restrict__ Wl,   // this layer's 256 floats
    float* __restrict__ x_out, float* __restrict__ xa_out,
    int s)                          // group stride: 0 for stage 0, 1 for stage 1
{
    const int blk = blockIdx.x;         // ((b*128 + g)*4 + n)
    const int n   = blk & 3;
    const int g   = (blk >> 2) & (kM - 1);
    const int b   = blk >> 9;
    const int t   = threadIdx.x;        // 0..63
    const int o   = t & 31;
    const int h   = t >> 5;

    // row index: ((g + o*s) % m) * CACHE + o
    const int r = (((g + o * s) & (kM - 1)) << 5) + o;
    const size_t base = ((size_t)(b * kN + r)) * kE + n * kCE + h * kH;

    float xi[kH], xa[kH], wi[kH], wj[kH];

    {
        const float4* xi4 = reinterpret_cast<const float4*>(x_in + base);
        const float4* xa4 = reinterpret_cast<const float4*>(xa_in + base);
        const float4* wi4 = reinterpret_cast<const float4*>(Wl + n * kCE + h * kH);
        const float4* wj4 = reinterpret_cast<const float4*>(Wl + kE + n * kCE + h * kH);
#pragma unroll
        for (int q = 0; q < kH / 4; ++q) {
            float4 v = xi4[q];
            xi[4 * q + 0] = v.x; xi[4 * q + 1] = v.y;
            xi[4 * q + 2] = v.z; xi[4 * q + 3] = v.w;
            float4 a = xa4[q];
            xa[4 * q + 0] = a.x; xa[4 * q + 1] = a.y;
            xa[4 * q + 2] = a.z; xa[4 * q + 3] = a.w;
            float4 u = wi4[q];
            wi[4 * q + 0] = u.x; wi[4 * q + 1] = u.y;
            wi[4 * q + 2] = u.z; wi[4 * q + 3] = u.w;
            float4 w = wj4[q];
            wj[4 * q + 0] = w.x; wj[4 * q + 1] = w.y;
            wj[4 * q + 2] = w.z; wj[4 * q + 3] = w.w;
        }
    }

    // bpermute byte-address base: source lane is (t & 32) + j
    const int srcbase = (t & 32) * 4;

#pragma unroll 8
    for (int j = 0; j < kCache; ++j) {
        const int srcaddr = srcbase + j * 4;

        // pull row j's slice from lane (h*32 + j); no barrier needed
        float xj[kH];
#pragma unroll
        for (int e = 0; e < kH; ++e) {
            xj[e] = __int_as_float(
                __builtin_amdgcn_ds_bpermute(srcaddr, __float_as_int(xi[e])));
        }

        // partial = dot16(xi_row, Wi_half) + dot16(xj, Wj_half); 4-way ILP
        float s0 = 0.f, s1 = 0.f, s2 = 0.f, s3 = 0.f;
#pragma unroll
        for (int e = 0; e < kH; e += 4) {
            s0 = fmaf(xi[e + 0], wi[e + 0], s0);
            s1 = fmaf(xi[e + 1], wi[e + 1], s1);
            s2 = fmaf(xi[e + 2], wi[e + 2], s2);
            s3 = fmaf(xi[e + 3], wi[e + 3], s3);
        }
#pragma unroll
        for (int e = 0; e < kH; e += 4) {
            s0 = fmaf(xj[e + 0], wj[e + 0], s0);
            s1 = fmaf(xj[e + 1], wj[e + 1], s1);
            s2 = fmaf(xj[e + 2], wj[e + 2], s2);
            s3 = fmaf(xj[e + 3], wj[e + 3], s3);
        }
        float part = (s0 + s1) + (s2 + s3);
        float sim  = part + __shfl_xor(part, 32, 64);
        const float hs = 0.5f * sim;

#pragma unroll
        for (int e = 0; e < kH; ++e) {
            float T = fmaf(hs, xj[e], 0.5f * xi[e]);
            // tanh(T) = 1 - 2/(exp2(2*log2e*T)+1); overflow/underflow -> +-1
            float t2 = __builtin_amdgcn_exp2f(T * 2.8853900817779268f);
            float F  = fmaf(-2.0f, __builtin_amdgcn_rcpf(t2 + 1.0f), 1.0f);
            xa[e] = fmaf(0.1f, F - xa[e], xa[e]);       // 0.9*xa + 0.1*F
            xi[e] = fmaf(0.1f, xa[e] - xi[e], xi[e]);   // 0.9*xi + 0.1*ya
        }
    }

    {
        float4* xo4 = reinterpret_cast<float4*>(x_out + base);
        float4* ao4 = reinterpret_cast<float4*>(xa_out + base);
#pragma unroll
        for (int q = 0; q < kH / 4; ++q) {
            float4 v;
            v.x = xi[4 * q + 0]; v.y = xi[4 * q + 1];
            v.z = xi[4 * q + 2]; v.w = xi[4 * q + 3];
            xo4[q] = v;
            float4 a;
            a.x = xa[4 * q + 0]; a.y = xa[4 * q + 1];
            a.z = xa[4 * q + 2]; a.w = xa[4 * q + 3];
            ao4[q] = a;
        }
    }
}

extern "C" void kernel_launch(void* const* d_in, const int* in_sizes, int n_in,
                              void* d_out, int out_size, void* d_ws, size_t ws_size,
                              hipStream_t stream) {
    const float* x  = (const float*)d_in[0];   // [B, N, E] fp32
    const float* xa = (const float*)d_in[1];   // [B, N, E] fp32
    const float* W  = (const float*)d_in[2];   // [2, 256] fp32

    float* x_out  = (float*)d_out;                       // first output
    float* xa_out = x_out + (size_t)kB * kN * kE;        // second output

    const dim3 grid(kB * kM * 4);   // 2048 single-wave blocks
    const dim3 block(64);

    // Layer 0 (stage 0, s = 0): d_in -> d_out
    ncn_layer_kernel<<<grid, block, 0, stream>>>(x, xa, W, x_out, xa_out, 0);
    // Layer 1 (stage 1, s = 1): d_out -> d_out (in-place; blocks own disjoint slices)
    ncn_layer_kernel<<<grid, block, 0, stream>>>(x_out, xa_out, W + 2 * kE,
                                                 x_out, xa_out, 1);
}

// Round 4
// 124.096 us; speedup vs baseline: 1.5878x; 1.0873x over previous
//
#include <hip/hip_runtime.h>

// NCN recurrence, 2 layers. B=4, N=4096, E=128, NK=4, ce=32, CACHE=32, m=128.
// 2048 independent [32 x 32] subproblems; one single-wave block each.
// Lane (h,o) owns feats [h*16,h*16+16) of row o, held as 8x float2 so the
// compiler emits packed v_pk_fma_f32 / v_pk_mul_f32 / v_pk_add_f32 (VOP3P,
// 2 f32 per issue) -> ~halves VALU issue count vs scalar.
// Scan j=0..31: row-j slice pulled via 16x ds_bpermute (no LDS, no barrier);
// sim reduction = one shfl_xor(32). tanh(T)=1-2/(exp2(2*log2e*T)+1) with the
// exp2 argument computed directly: arg = L1*xi + (L1*sim)*xj  (T never
// materialized). Unclamped: exp2 over/underflow gives the exact +-1 limit.
// Keep hardware-accurate tanh: the recurrence amplifies per-step error ~1e3.
// Blocks own disjoint (row, feat-slice) sets -> layer 1 runs in-place.

namespace {
constexpr int kB = 4;
constexpr int kN = 4096;
constexpr int kE = 128;
constexpr int kCE = 32;          // E / NK
constexpr int kH  = 16;          // feats per lane
constexpr int kQ  = kH / 2;      // float2 count
constexpr int kCache = 32;
constexpr int kM = kN / kCache;  // 128 groups per batch

typedef __attribute__((ext_vector_type(2))) float f32x2;

__device__ __forceinline__ f32x2 pk_fma(f32x2 a, f32x2 b, f32x2 c) {
    return __builtin_elementwise_fma(a, b, c);
}
}  // namespace

__global__ void __launch_bounds__(64) ncn_layer_kernel(
    const float* __restrict__ x_in, const float* __restrict__ xa_in,
    const float* __restrict__ Wl,   // this layer's 256 floats
    float* __restrict__ x_out, float* __restrict__ xa_out,
    int s)                          // group stride: 0 for stage 0, 1 for stage 1
{
    const int blk = blockIdx.x;         // ((b*128 + g)*4 + n)
    const int n   = blk & 3;
    const int g   = (blk >> 2) & (kM - 1);
    const int b   = blk >> 9;
    const int t   = threadIdx.x;        // 0..63
    const int o   = t & 31;
    const int h   = t >> 5;

    // row index: ((g + o*s) % m) * CACHE + o
    const int r = (((g + o * s) & (kM - 1)) << 5) + o;
    const size_t base = ((size_t)(b * kN + r)) * kE + n * kCE + h * kH;

    f32x2 xi[kQ], xa[kQ], wi[kQ], wj[kQ];

    {
        const float4* xi4 = reinterpret_cast<const float4*>(x_in + base);
        const float4* xa4 = reinterpret_cast<const float4*>(xa_in + base);
        const float4* wi4 = reinterpret_cast<const float4*>(Wl + n * kCE + h * kH);
        const float4* wj4 = reinterpret_cast<const float4*>(Wl + kE + n * kCE + h * kH);
#pragma unroll
        for (int q = 0; q < kQ / 2; ++q) {
            float4 v = xi4[q];
            xi[2 * q + 0] = f32x2{v.x, v.y}; xi[2 * q + 1] = f32x2{v.z, v.w};
            float4 a = xa4[q];
            xa[2 * q + 0] = f32x2{a.x, a.y}; xa[2 * q + 1] = f32x2{a.z, a.w};
            float4 u = wi4[q];
            wi[2 * q + 0] = f32x2{u.x, u.y}; wi[2 * q + 1] = f32x2{u.z, u.w};
            float4 w = wj4[q];
            wj[2 * q + 0] = f32x2{w.x, w.y}; wj[2 * q + 1] = f32x2{w.z, w.w};
        }
    }

    // bpermute byte-address base: source lane is (t & 32) + j
    const int srcbase = (t & 32) * 4;
    constexpr float L1 = 1.4426950408889634f;   // log2(e); arg = 2*L1*T

#pragma unroll 4
    for (int j = 0; j < kCache; ++j) {
        const int srcaddr = srcbase + j * 4;

        // pull row j's slice from lane (h*32 + j); no barrier needed
        f32x2 xj[kQ];
#pragma unroll
        for (int q = 0; q < kQ; ++q) {
            xj[q].x = __int_as_float(
                __builtin_amdgcn_ds_bpermute(srcaddr, __float_as_int(xi[q].x)));
            xj[q].y = __int_as_float(
                __builtin_amdgcn_ds_bpermute(srcaddr, __float_as_int(xi[q].y)));
        }

        // partial = dot16(xi,wi) + dot16(xj,wj); 2 packed accumulators (4-way)
        f32x2 s01 = xi[0] * wi[0];
        f32x2 s23 = xi[1] * wi[1];
#pragma unroll
        for (int q = 2; q < kQ; q += 2) {
            s01 = pk_fma(xi[q + 0], wi[q + 0], s01);
            s23 = pk_fma(xi[q + 1], wi[q + 1], s23);
        }
#pragma unroll
        for (int q = 0; q < kQ; q += 2) {
            s01 = pk_fma(xj[q + 0], wj[q + 0], s01);
            s23 = pk_fma(xj[q + 1], wj[q + 1], s23);
        }
        f32x2 sv = s01 + s23;
        float part = sv.x + sv.y;
        float sim  = part + __shfl_xor(part, 32, 64);
        const float hv = L1 * sim;          // arg = L1*xi + hv*xj
        const f32x2 hv2 = {hv, hv};
        const f32x2 l12 = {L1, L1};
        const f32x2 one = {1.0f, 1.0f};
        const f32x2 m2  = {-2.0f, -2.0f};
        const f32x2 p1  = {0.1f, 0.1f};

#pragma unroll
        for (int q = 0; q < kQ; ++q) {
            f32x2 arg = pk_fma(xj[q], hv2, xi[q] * l12);
            f32x2 t2;
            t2.x = __builtin_amdgcn_exp2f(arg.x);
            t2.y = __builtin_amdgcn_exp2f(arg.y);
            f32x2 den = t2 + one;
            f32x2 rc;
            rc.x = __builtin_amdgcn_rcpf(den.x);
            rc.y = __builtin_amdgcn_rcpf(den.y);
            f32x2 F = pk_fma(m2, rc, one);            // tanh(T)
            xa[q] = pk_fma(p1, F - xa[q], xa[q]);     // 0.9*xa + 0.1*F
            xi[q] = pk_fma(p1, xa[q] - xi[q], xi[q]); // 0.9*xi + 0.1*ya
        }
    }

    {
        float4* xo4 = reinterpret_cast<float4*>(x_out + base);
        float4* ao4 = reinterpret_cast<float4*>(xa_out + base);
#pragma unroll
        for (int q = 0; q < kQ / 2; ++q) {
            float4 v;
            v.x = xi[2 * q + 0].x; v.y = xi[2 * q + 0].y;
            v.z = xi[2 * q + 1].x; v.w = xi[2 * q + 1].y;
            xo4[q] = v;
            float4 a;
            a.x = xa[2 * q + 0].x; a.y = xa[2 * q + 0].y;
            a.z = xa[2 * q + 1].x; a.w = xa[2 * q + 1].y;
            ao4[q] = a;
        }
    }
}

extern "C" void kernel_launch(void* const* d_in, const int* in_sizes, int n_in,
                              void* d_out, int out_size, void* d_ws, size_t ws_size,
                              hipStream_t stream) {
    const float* x  = (const float*)d_in[0];   // [B, N, E] fp32
    const float* xa = (const float*)d_in[1];   // [B, N, E] fp32
    const float* W  = (const float*)d_in[2];   // [2, 256] fp32

    float* x_out  = (float*)d_out;                       // first output
    float* xa_out = x_out + (size_t)kB * kN * kE;        // second output

    const dim3 grid(kB * kM * 4);   // 2048 single-wave blocks
    const dim3 block(64);

    // Layer 0 (stage 0, s = 0): d_in -> d_out
    ncn_layer_kernel<<<grid, block, 0, stream>>>(x, xa, W, x_out, xa_out, 0);
    // Layer 1 (stage 1, s = 1): d_out -> d_out (in-place; blocks own disjoint slices)
    ncn_layer_kernel<<<grid, block, 0, stream>>>(x_out, xa_out, W + 2 * kE,
                                                 x_out, xa_out, 1);
}

// Round 5
// 121.917 us; speedup vs baseline: 1.6162x; 1.0179x over previous
//
#include <hip/hip_runtime.h>

// NCN recurrence, 2 layers. B=4, N=4096, E=128, NK=4, ce=32, CACHE=32, m=128.
// 2048 independent [32 x 32] subproblems; one single-wave block each.
// Lane (h,o) owns feats [h*16,h*16+16) of row o as 8x float2 (packed VOP3P).
//
// R5 restructure: ONE DS round-trip per scan step (was two serial).
//   sim(i) = di(i) + dj,  di = dot32(row i, Wi),  dj = dot32(row j, Wj).
//   - pj = dot16(own xi, wj) per lane; dj = bperm(pj, j) + bperm(pj, 32+j)
//     (uniform-address bpermutes, independent of the xj pulls).
//   - di = part + shfl_xor(part, 32), independent of everything else.
//   - 16 xj bpermutes depend only on xi -> all 19 DS ops issue back-to-back,
//     latency covered by the 16 dot-fmas + hoisted elementwise pre-work
//     (xi*L1, 0.9*xa+0.1, 0.9*xi depend only on old state).
// Weights pre-scaled by L1=log2(e): dots produce L1*sim directly;
// tanh via 0.1*F = 0.1 - 0.2*rcp(exp2(arg)+1), arg = L1*xi + (L1*sim)*xj.
// Unclamped exp2: over/underflow gives the exact +-1 tanh limit.
// Blocks own disjoint (row, feat-slice) sets -> layer 1 runs in-place.

namespace {
constexpr int kB = 4;
constexpr int kN = 4096;
constexpr int kE = 128;
constexpr int kCE = 32;          // E / NK
constexpr int kH  = 16;          // feats per lane
constexpr int kQ  = kH / 2;      // float2 count
constexpr int kCache = 32;
constexpr int kM = kN / kCache;  // 128 groups per batch

typedef __attribute__((ext_vector_type(2))) float f32x2;

__device__ __forceinline__ f32x2 pk_fma(f32x2 a, f32x2 b, f32x2 c) {
    return __builtin_elementwise_fma(a, b, c);
}
}  // namespace

__global__ void __launch_bounds__(64) ncn_layer_kernel(
    const float* __restrict__ x_in, const float* __restrict__ xa_in,
    const float* __restrict__ Wl,   // this layer's 256 floats
    float* __restrict__ x_out, float* __restrict__ xa_out,
    int s)                          // group stride: 0 for stage 0, 1 for stage 1
{
    const int blk = blockIdx.x;         // ((b*128 + g)*4 + n)
    const int n   = blk & 3;
    const int g   = (blk >> 2) & (kM - 1);
    const int b   = blk >> 9;
    const int t   = threadIdx.x;        // 0..63
    const int o   = t & 31;
    const int h   = t >> 5;

    // row index: ((g + o*s) % m) * CACHE + o
    const int r = (((g + o * s) & (kM - 1)) << 5) + o;
    const size_t base = ((size_t)(b * kN + r)) * kE + n * kCE + h * kH;

    constexpr float L1 = 1.4426950408889634f;   // log2(e)

    f32x2 xi[kQ], xa[kQ], wi[kQ], wj[kQ];

    {
        const float4* xi4 = reinterpret_cast<const float4*>(x_in + base);
        const float4* xa4 = reinterpret_cast<const float4*>(xa_in + base);
        const float4* wi4 = reinterpret_cast<const float4*>(Wl + n * kCE + h * kH);
        const float4* wj4 = reinterpret_cast<const float4*>(Wl + kE + n * kCE + h * kH);
#pragma unroll
        for (int q = 0; q < kQ / 2; ++q) {
            float4 v = xi4[q];
            xi[2 * q + 0] = f32x2{v.x, v.y}; xi[2 * q + 1] = f32x2{v.z, v.w};
            float4 a = xa4[q];
            xa[2 * q + 0] = f32x2{a.x, a.y}; xa[2 * q + 1] = f32x2{a.z, a.w};
            float4 u = wi4[q];   // pre-scale by L1: dots yield L1*sim directly
            wi[2 * q + 0] = f32x2{u.x * L1, u.y * L1};
            wi[2 * q + 1] = f32x2{u.z * L1, u.w * L1};
            float4 w = wj4[q];
            wj[2 * q + 0] = f32x2{w.x * L1, w.y * L1};
            wj[2 * q + 1] = f32x2{w.z * L1, w.w * L1};
        }
    }

    // bpermute byte-address base for xj pulls: source lane (t & 32) + j
    const int srcbase = (t & 32) * 4;

#pragma unroll 8
    for (int j = 0; j < kCache; ++j) {
        const int srcaddr = srcbase + j * 4;

        // --- issue all DS ops for this step in one batch ---
        // (1) row-j slice pull (dep: xi only)
        f32x2 xj[kQ];
#pragma unroll
        for (int q = 0; q < kQ; ++q) {
            xj[q].x = __int_as_float(
                __builtin_amdgcn_ds_bpermute(srcaddr, __float_as_int(xi[q].x)));
            xj[q].y = __int_as_float(
                __builtin_amdgcn_ds_bpermute(srcaddr, __float_as_int(xi[q].y)));
        }

        // (2) own-row dots: part = dot16(xi,wi), pj = dot16(xi,wj)
        f32x2 a01 = xi[0] * wi[0];
        f32x2 a23 = xi[1] * wi[1];
        f32x2 b01 = xi[0] * wj[0];
        f32x2 b23 = xi[1] * wj[1];
#pragma unroll
        for (int q = 2; q < kQ; q += 2) {
            a01 = pk_fma(xi[q + 0], wi[q + 0], a01);
            a23 = pk_fma(xi[q + 1], wi[q + 1], a23);
            b01 = pk_fma(xi[q + 0], wj[q + 0], b01);
            b23 = pk_fma(xi[q + 1], wj[q + 1], b23);
        }
        f32x2 av = a01 + a23;
        f32x2 bv = b01 + b23;
        float part = av.x + av.y;     // L1 * dot16(row i, Wi-half)
        float pj   = bv.x + bv.y;     // L1 * dot16(row i, Wj-half)

        // (3) cross-lane: di partner + dj from row-j's two half-lanes
        float di_o = __shfl_xor(part, 32, 64);
        float dj0  = __int_as_float(
            __builtin_amdgcn_ds_bpermute(j * 4, __float_as_int(pj)));
        float dj1  = __int_as_float(
            __builtin_amdgcn_ds_bpermute(128 + j * 4, __float_as_int(pj)));

        // --- hoisted elementwise pre-work (independent of DS results) ---
        f32x2 xiL[kQ], t1[kQ], u9[kQ];
        const f32x2 l12 = {L1, L1};
        const f32x2 c9  = {0.9f, 0.9f};
        const f32x2 c01 = {0.1f, 0.1f};
#pragma unroll
        for (int q = 0; q < kQ; ++q) {
            xiL[q] = xi[q] * l12;                       // L1 * xi
            t1[q]  = pk_fma(c9, xa[q], c01);            // 0.9*xa + 0.1
            u9[q]  = xi[q] * c9;                        // 0.9*xi
        }

        const float sim = (part + di_o) + (dj0 + dj1);  // = L1 * sim_true
        const f32x2 sv  = {sim, sim};
        const f32x2 one = {1.0f, 1.0f};
        const f32x2 m02 = {-0.2f, -0.2f};

#pragma unroll
        for (int q = 0; q < kQ; ++q) {
            f32x2 arg = pk_fma(xj[q], sv, xiL[q]);      // 2*L1*T
            f32x2 t2;
            t2.x = __builtin_amdgcn_exp2f(arg.x);
            t2.y = __builtin_amdgcn_exp2f(arg.y);
            f32x2 den = t2 + one;
            f32x2 rc;
            rc.x = __builtin_amdgcn_rcpf(den.x);
            rc.y = __builtin_amdgcn_rcpf(den.y);
            xa[q] = pk_fma(m02, rc, t1[q]);             // 0.9*xa + 0.1*tanh(T)
            xi[q] = pk_fma(c01, xa[q], u9[q]);          // 0.9*xi + 0.1*ya
        }
    }

    {
        float4* xo4 = reinterpret_cast<float4*>(x_out + base);
        float4* ao4 = reinterpret_cast<float4*>(xa_out + base);
#pragma unroll
        for (int q = 0; q < kQ / 2; ++q) {
            float4 v;
            v.x = xi[2 * q + 0].x; v.y = xi[2 * q + 0].y;
            v.z = xi[2 * q + 1].x; v.w = xi[2 * q + 1].y;
            xo4[q] = v;
            float4 a;
            a.x = xa[2 * q + 0].x; a.y = xa[2 * q + 0].y;
            a.z = xa[2 * q + 1].x; a.w = xa[2 * q + 1].y;
            ao4[q] = a;
        }
    }
}

extern "C" void kernel_launch(void* const* d_in, const int* in_sizes, int n_in,
                              void* d_out, int out_size, void* d_ws, size_t ws_size,
                              hipStream_t stream) {
    const float* x  = (const float*)d_in[0];   // [B, N, E] fp32
    const float* xa = (const float*)d_in[1];   // [B, N, E] fp32
    const float* W  = (const float*)d_in[2];   // [2, 256] fp32

    float* x_out  = (float*)d_out;                       // first output
    float* xa_out = x_out + (size_t)kB * kN * kE;        // second output

    const dim3 grid(kB * kM * 4);   // 2048 single-wave blocks
    const dim3 block(64);

    // Layer 0 (stage 0, s = 0): d_in -> d_out
    ncn_layer_kernel<<<grid, block, 0, stream>>>(x, xa, W, x_out, xa_out, 0);
    // Layer 1 (stage 1, s = 1): d_out -> d_out (in-place; blocks own disjoint slices)
    ncn_layer_kernel<<<grid, block, 0, stream>>>(x_out, xa_out, W + 2 * kE,
                                                 x_out, xa_out, 1);
}